// Round 15
// baseline (437.327 us; speedup 1.0000x reference)
//
#include <hip/hip_runtime.h>
#include <hip/hip_cooperative_groups.h>
#include <math.h>

#define N_NODES 50000
#define N_EDGES 400000
#define EN_TOT  450000
#define IN_DIM  128
#define H_HEADS 8
#define C_CH    32
#define HC      256
#define NEG_SLOPE 0.2f
#define MAXDEG 64      // LDS stash cap; global fallback beyond (max deg here ~30)

typedef __attribute__((ext_vector_type(8))) short bf16x8;
typedef __attribute__((ext_vector_type(4))) float f32x4;

// ---------------- workspace layout (float slots) ----------------
// UNIT DISCIPLINE: sizes in FLOAT slots; bf16 regions = count/2 slots.
#define OFF_XLB   0                                   // x_l bf16 [N,256] -> N*128 floats
#define OFF_XRB   (OFF_XLB + N_NODES * 128)           // x_r bf16 [N,256]
#define OFF_PROJ  (OFF_XRB + N_NODES * 128)           // proj fp32 [N,32]
#define OFF_AEXP  (OFF_PROJ + N_NODES * C_CH)         // aexp [E+N,8] fp32 (overflow fallback only)
#define OFF_WCAT  (OFF_AEXP + EN_TOT * H_HEADS)       // Wcat bf16 [544,128]: 69632 shorts = 34816 floats
#define OFF_PART  (OFF_WCAT + 34816)                  // partial sums [1024]
#define OFF_MEAN  (OFF_PART + 1024)                   // mean scalar [1]
#define OFF_PAD   (OFF_MEAN + 1)                      // pad to 16B boundary
#define OFF_CSR2  (OFF_PAD + 3)                       // packed csr int2 {src|eav_bf16<<16, eid} [E+N]
#define OFF_DEG   (OFF_CSR2 + EN_TOT * 2)             // deg  [N]
#define OFF_OFFS  (OFF_DEG + N_NODES)                 // offs [N+1]
#define OFF_CUR   (OFF_OFFS + N_NODES + 1)            // cursor [N]
#define OFF_BSUM  (OFF_CUR + N_NODES)                 // block sums [256]

#define SCAN_B 196   // ceil(50000/256)
#define CSRB   784   // cooperative csr-build grid (>=SCAN_B; 784*256 threads for scatter)
#define LOG2E 1.4426950408889634f

// ---------------- fp32 -> bf16 (RNE) ----------------
__device__ __forceinline__ unsigned f2bf(float f) {
    unsigned u = __float_as_uint(f);
    u += 0x7fffu + ((u >> 16) & 1u);
    return u >> 16;
}
__device__ __forceinline__ float bflo(unsigned u) { return __uint_as_float(u << 16); }
__device__ __forceinline__ float bfhi(unsigned u) { return __uint_as_float(u & 0xffff0000u); }

// ---------------- fused: weight convert + dst-histogram + edge_attr partials ----------------
#define WCHUNKS 8704              // 544*128/8
__global__ __launch_bounds__(256) void pre_kernel(
    const float* __restrict__ Wl, const float* __restrict__ Wr, const float* __restrict__ Wproj,
    unsigned short* __restrict__ wcat,
    const int* __restrict__ ei, const float* __restrict__ ea,
    int* __restrict__ deg, float* __restrict__ part)
{
    __shared__ float sd[256];
    const int t = threadIdx.x;
    const int g = blockIdx.x * 256 + t;

    if (g < WCHUNKS) {
        int j = (g * 8) >> 7, k = (g * 8) & 127;
        const float* src = (j < 256 ? Wl + (size_t)j * 128
                                    : (j < 512 ? Wr + (size_t)(j - 256) * 128
                                               : Wproj + (size_t)(j - 512) * 128)) + k;
        float4 a = ((const float4*)src)[0];
        float4 b = ((const float4*)src)[1];
        uint4 o;
        o.x = f2bf(a.x) | (f2bf(a.y) << 16);
        o.y = f2bf(a.z) | (f2bf(a.w) << 16);
        o.z = f2bf(b.x) | (f2bf(b.y) << 16);
        o.w = f2bf(b.z) | (f2bf(b.w) << 16);
        ((uint4*)wcat)[g] = o;
    }

    float s = 0.f;
    for (int i = g; i < N_EDGES; i += 1024 * 256) s += ea[i];
    for (int i = g; i < EN_TOT; i += 1024 * 256) {
        int d = (i < N_EDGES) ? ei[N_EDGES + i] : (i - N_EDGES);
        atomicAdd(&deg[d], 1);
    }
    sd[t] = s; __syncthreads();
    for (int w = 128; w > 0; w >>= 1) { if (t < w) sd[t] += sd[t + w]; __syncthreads(); }
    if (t == 0) part[blockIdx.x] = sd[0];
}

// ---------------- cooperative CSR build: scan(3 phases) + mean + scatter in ONE dispatch ----------------
// Replaces scan_part / mid / scan_final / scatter kernels (saves 3 launch gaps).
__global__ __launch_bounds__(256) void csr_build_kernel(
    const int* __restrict__ ei, const float* __restrict__ ea,
    const float* __restrict__ part,
    int* __restrict__ deg, int* __restrict__ bsum,
    int* __restrict__ offs, int* __restrict__ cur,
    float* __restrict__ mean_out, int2* __restrict__ csr2)
{
    namespace cg = cooperative_groups;
    cg::grid_group grid = cg::this_grid();
    __shared__ int sd[256];
    __shared__ float sf[256];
    const int t = threadIdx.x;
    const int b = blockIdx.x;

    // phase 1: per-block sums of deg (blocks 0..SCAN_B-1)
    if (b < SCAN_B) {
        int i = b * 256 + t;
        int v = (i < N_NODES) ? deg[i] : 0;
        sd[t] = v; __syncthreads();
        for (int w = 128; w > 0; w >>= 1) { if (t < w) sd[t] += sd[t + w]; __syncthreads(); }
        if (t == 0) bsum[b] = sd[0];
    }
    grid.sync();

    // phase 2 (block 0): exclusive scan of bsum + edge_attr mean finalize
    if (b == 0) {
        float s = part[t] + part[t + 256] + part[t + 512] + part[t + 768];
        sf[t] = s;
        int v = (t < SCAN_B) ? bsum[t] : 0;
        sd[t] = v; __syncthreads();
        for (int w = 128; w > 0; w >>= 1) { if (t < w) sf[t] += sf[t + w]; __syncthreads(); }
        if (t == 0) mean_out[0] = sf[0] / (float)N_EDGES;
        #pragma unroll
        for (int ofs = 1; ofs < 256; ofs <<= 1) {
            int u = (t >= ofs) ? sd[t - ofs] : 0;
            __syncthreads();
            sd[t] += u;
            __syncthreads();
        }
        if (t < SCAN_B) bsum[t] = sd[t] - v;   // exclusive
    }
    grid.sync();

    // phase 3: offs/cur (blocks 0..SCAN_B-1)
    if (b < SCAN_B) {
        int i = b * 256 + t;
        int v = (i < N_NODES) ? deg[i] : 0;
        sd[t] = v; __syncthreads();
        #pragma unroll
        for (int ofs = 1; ofs < 256; ofs <<= 1) {
            int u = (t >= ofs) ? sd[t - ofs] : 0;
            __syncthreads();
            sd[t] += u;
            __syncthreads();
        }
        int excl = bsum[b] + sd[t] - v;
        if (i < N_NODES) { offs[i] = excl; cur[i] = excl; }
        if (i == N_NODES - 1) offs[N_NODES] = excl + v;
    }
    grid.sync();

    // phase 4: scatter (all blocks, grid-stride)
    const float mv = mean_out[0];
    const int stride = CSRB * 256;
    for (int e = b * 256 + t; e < EN_TOT; e += stride) {
        int s, d; float eav;
        if (e < N_EDGES) { s = ei[e]; d = ei[N_EDGES + e]; eav = ea[e]; }
        else { s = e - N_EDGES; d = s; eav = mv; }
        int pos = atomicAdd(&cur[d], 1);
        csr2[pos] = make_int2(s | (int)(f2bf(eav) << 16), e);   // src < 65536 OK (N=50000)
    }
}

// ---------------- MFMA GEMM: fp32 x converted inline, bf16 out xl/xr, fp32 proj ----------------
// Epilogue: bf16 tiles staged in LDS (stride 72 shorts, 16B-aligned), then 16B
// coalesced uint4 stores (8x fewer store instructions than per-element shorts).
#define GM 128
#define GN 64
#define CST 72   // C-staging stride in shorts (144B rows)

__global__ __launch_bounds__(256) void gemm_mfma_kernel(
    const float* __restrict__ x, const unsigned short* __restrict__ wcat,
    unsigned short* __restrict__ xlb, unsigned short* __restrict__ xrb,
    float* __restrict__ proj)
{
    __shared__ unsigned short As[GM * 128];   // 32 KB (staging A; reused for C)
    __shared__ unsigned short Bs[GN * 128];   // 16 KB
    const int t = threadIdx.x;
    const int m0 = blockIdx.x * GM;
    const int n0 = blockIdx.y * GN;

    #pragma unroll
    for (int cc = 0; cc < 8; ++cc) {
        int c = t + cc * 256;
        int r = c >> 4;
        int k0 = (c & 15) * 8;
        int row = m0 + r;
        uint4 o = make_uint4(0, 0, 0, 0);
        if (row < N_NODES) {
            const float* p = x + (size_t)row * IN_DIM + k0;
            float4 a = ((const float4*)p)[0];
            float4 b = ((const float4*)p)[1];
            o.x = f2bf(a.x) | (f2bf(a.y) << 16);
            o.y = f2bf(a.z) | (f2bf(a.w) << 16);
            o.z = f2bf(b.x) | (f2bf(b.y) << 16);
            o.w = f2bf(b.z) | (f2bf(b.w) << 16);
        }
        int byte = (r * 256 + k0 * 2) ^ ((r & 7) << 4);
        *((uint4*)((char*)As + byte)) = o;
    }
    #pragma unroll
    for (int cc = 0; cc < 4; ++cc) {
        int c = t + cc * 256;
        int r = c >> 4;
        int k0 = (c & 15) * 8;
        int j = n0 + r;
        uint4 v = make_uint4(0, 0, 0, 0);
        if (j < 544) v = *((const uint4*)(wcat + (size_t)j * 128 + k0));
        int byte = (r * 256 + k0 * 2) ^ ((r & 7) << 4);
        *((uint4*)((char*)Bs + byte)) = v;
    }
    __syncthreads();

    const int wid = t >> 6, lane = t & 63;
    const int wr = wid >> 1, wc = wid & 1;
    const int lrow = lane & 15;
    const int kgrp = (lane >> 4) * 8;

    f32x4 acc[4][2] = {};
    #pragma unroll
    for (int kk = 0; kk < 4; ++kk) {
        bf16x8 a[4], b[2];
        #pragma unroll
        for (int fm = 0; fm < 4; ++fm) {
            int r = wr * 64 + fm * 16 + lrow;
            int byte = (r * 256 + (kk * 32 + kgrp) * 2) ^ ((r & 7) << 4);
            a[fm] = *((const bf16x8*)((const char*)As + byte));
        }
        #pragma unroll
        for (int fn = 0; fn < 2; ++fn) {
            int r = wc * 32 + fn * 16 + lrow;
            int byte = (r * 256 + (kk * 32 + kgrp) * 2) ^ ((r & 7) << 4);
            b[fn] = *((const bf16x8*)((const char*)Bs + byte));
        }
        #pragma unroll
        for (int fm = 0; fm < 4; ++fm)
            #pragma unroll
            for (int fn = 0; fn < 2; ++fn)
                acc[fm][fn] = __builtin_amdgcn_mfma_f32_16x16x32_bf16(a[fm], b[fn], acc[fm][fn], 0, 0, 0);
    }

    // C layout: row = (lane>>4)*4 + reg, col = lane&15  (m89-verified)
    const int crow0 = (lane >> 4) * 4;
    const int ccol = lane & 15;

    if (n0 < 512) {
        __syncthreads();   // all MFMA reads of As complete
        unsigned short* Cs = As;   // [GM][CST] shorts
        #pragma unroll
        for (int fm = 0; fm < 4; ++fm)
            #pragma unroll
            for (int fn = 0; fn < 2; ++fn)
                #pragma unroll
                for (int r = 0; r < 4; ++r) {
                    int lr = wr * 64 + fm * 16 + crow0 + r;    // 0..127
                    int lc = wc * 32 + fn * 16 + ccol;         // 0..63
                    Cs[lr * CST + lc] = (unsigned short)f2bf(acc[fm][fn][r]);
                }
        __syncthreads();
        unsigned short* dst = (n0 < 256) ? xlb : xrb;
        const int colbase = n0 & 255;
        #pragma unroll
        for (int cc = 0; cc < 4; ++cc) {
            int c = t + cc * 256;        // 0..1023
            int r = c >> 3;              // 0..127
            int c8 = (c & 7) * 8;        // col 0,8,..,56
            int row = m0 + r;
            if (row < N_NODES) {
                uint4 v = *((const uint4*)(Cs + r * CST + c8));
                *((uint4*)(dst + (size_t)row * HC + colbase + c8)) = v;
            }
        }
    } else {
        #pragma unroll
        for (int fm = 0; fm < 4; ++fm)
            #pragma unroll
            for (int fn = 0; fn < 2; ++fn)
                #pragma unroll
                for (int r = 0; r < 4; ++r) {
                    int row = m0 + wr * 64 + fm * 16 + crow0 + r;
                    int col = n0 + wc * 32 + fn * 16 + ccol;
                    if (row >= N_NODES || col >= 544) continue;
                    proj[(size_t)row * C_CH + (col - 512)] = acc[fm][fn][r];
                }
    }
}

// ---------------- fused node aggregation: scalar math + int2 CSR + exp2 fold + LDS stash ----------------
// One wave per node; 32 lanes/edge (8 ch/lane), 2 edges/wave-step, 1-pair pipeline.
// Scalar math (packed-f32 regressed twice: r9, r12). att pre-scaled by LOG2E so
// exp2f = bare v_exp_f32. aexp/eid stashed in per-wave LDS. STRUCTURAL FLOOR:
// VALUBusy ~83%, 5 variants (r8-r12) all >= 69.4us — do not restructure again.
__global__ __launch_bounds__(256) void node_agg_kernel(
    const int* __restrict__ offs, const int2* __restrict__ csr2,
    const float* __restrict__ We, const float* __restrict__ att,
    const unsigned short* __restrict__ xlb, const unsigned short* __restrict__ xrb,
    const float* __restrict__ proj, const float* __restrict__ bias,
    float* __restrict__ aexp_ovf, float* __restrict__ alpha_out, float* __restrict__ xnew)
{
    __shared__ float s_aexp[4][MAXDEG][H_HEADS];   // 8 KB
    __shared__ int   s_eid[4][MAXDEG];             // 1 KB
    const int w = threadIdx.x >> 6;
    const int l = threadIdx.x & 63;
    const int d = blockIdx.x * 4 + w;
    if (d >= N_NODES) return;
    const int half = l >> 5;     // which edge of the pair this lane works on
    const int sl = l & 31;       // channel block: ch sl*8 .. sl*8+7 (head sl>>2)

    const float4 we0 = ((const float4*)We)[sl * 2];
    const float4 we1 = ((const float4*)We)[sl * 2 + 1];
    const float4 at0 = ((const float4*)att)[sl * 2];
    const float4 at1 = ((const float4*)att)[sl * 2 + 1];
    const float wev[8] = {we0.x, we0.y, we0.z, we0.w, we1.x, we1.y, we1.z, we1.w};
    const float atv[8] = {at0.x * LOG2E, at0.y * LOG2E, at0.z * LOG2E, at0.w * LOG2E,
                          at1.x * LOG2E, at1.y * LOG2E, at1.z * LOG2E, at1.w * LOG2E};

    const uint4 vru = ((const uint4*)(xrb + (size_t)d * HC))[sl];
    float vr[8];
    vr[0] = bflo(vru.x); vr[1] = bfhi(vru.x); vr[2] = bflo(vru.y); vr[3] = bfhi(vru.y);
    vr[4] = bflo(vru.z); vr[5] = bfhi(vru.z); vr[6] = bflo(vru.w); vr[7] = bfhi(vru.w);

    const int beg = offs[d];
    const int end = offs[d + 1];

    float acc[8] = {0.f, 0.f, 0.f, 0.f, 0.f, 0.f, 0.f, 0.f};
    float den = 0.f;

    int i = beg;
    int2 c0 = make_int2(0, 0);
    uint4 vl0 = make_uint4(0, 0, 0, 0);
    if (i + half < end) {
        c0 = csr2[i + half];
        vl0 = ((const uint4*)(xlb + (size_t)(c0.x & 0xffff) * HC))[sl];
    }
    while (i < end) {
        const int ni = i + 2;
        int2 c1 = make_int2(0, 0);
        uint4 vl1 = make_uint4(0, 0, 0, 0);
        if (ni + half < end) {
            c1 = csr2[ni + half];
            vl1 = ((const uint4*)(xlb + (size_t)(c1.x & 0xffff) * HC))[sl];
        }

        const float ea = bfhi((unsigned)c0.x);   // eav bf16 in high 16 bits
        float xv[8];
        xv[0] = bflo(vl0.x); xv[1] = bfhi(vl0.x); xv[2] = bflo(vl0.y); xv[3] = bfhi(vl0.y);
        xv[4] = bflo(vl0.z); xv[5] = bfhi(vl0.z); xv[6] = bflo(vl0.w); xv[7] = bfhi(vl0.w);

        float tt = 0.f;
        #pragma unroll
        for (int j = 0; j < 8; ++j) {
            float m = xv[j] + vr[j] + ea * wev[j];
            m = fmaxf(m, NEG_SLOPE * m);      // leaky_relu (slope<1)
            tt += m * atv[j];
        }
        tt += __shfl_xor(tt, 1);
        tt += __shfl_xor(tt, 2);
        float aex = exp2f(tt);                // v_exp_f32; LOG2E folded into atv
        const bool valid = (i + half) < end;
        aex = valid ? aex : 0.f;
        const int li = i + half - beg;        // local edge index within node
        if (valid && (sl & 3) == 0) {
            if (li < MAXDEG) s_aexp[w][li][sl >> 2] = aex;
            else             aexp_ovf[(size_t)c0.y * H_HEADS + (sl >> 2)] = aex;
        }
        if (valid && sl == 0 && li < MAXDEG) s_eid[w][li] = c0.y;
        #pragma unroll
        for (int j = 0; j < 8; ++j) acc[j] += aex * xv[j];
        den += aex;

        c0 = c1; vl0 = vl1; i = ni;
    }

    // merge the two edge-halves (same channels, same head)
    den += __shfl_xor(den, 32);
    #pragma unroll
    for (int j = 0; j < 8; ++j) acc[j] += __shfl_xor(acc[j], 32);

    // ---- fused alpha from LDS stash: lane 4h holds den of head h
    const float den_h = __shfl(den, ((l & 7) << 2));
    const float rden = 1.f / den_h;
    for (int b = beg; b < end; b += 8) {
        const int idx = b + (l >> 3);
        if (idx < end) {
            const int li = idx - beg;
            int e; float ax;
            if (li < MAXDEG) { e = s_eid[w][li]; ax = s_aexp[w][li][l & 7]; }
            else { e = csr2[idx].y; ax = aexp_ovf[(size_t)e * H_HEADS + (l & 7)]; }
            alpha_out[(size_t)e * H_HEADS + (l & 7)] = ax * rden;
        }
    }

    // ---- normalize per head, mean over heads, epilogue
    const float inv = 1.f / den;
    #pragma unroll
    for (int j = 0; j < 8; ++j) acc[j] *= inv;
    #pragma unroll
    for (int mask = 4; mask <= 16; mask <<= 1)
        #pragma unroll
        for (int j = 0; j < 8; ++j) acc[j] += __shfl_xor(acc[j], mask);
    // lane sl (<4, half 0) holds head-summed channels sl*8 .. sl*8+7
    if (half == 0 && sl < 4) {
        const float4 bi0 = ((const float4*)bias)[sl * 2];
        const float4 bi1 = ((const float4*)bias)[sl * 2 + 1];
        const float4 pr0 = ((const float4*)(proj + (size_t)d * C_CH))[sl * 2];
        const float4 pr1 = ((const float4*)(proj + (size_t)d * C_CH))[sl * 2 + 1];
        float4 r0, r1;
        r0.x = fmaxf(acc[0] * 0.125f + bi0.x, 0.f) + pr0.x;
        r0.y = fmaxf(acc[1] * 0.125f + bi0.y, 0.f) + pr0.y;
        r0.z = fmaxf(acc[2] * 0.125f + bi0.z, 0.f) + pr0.z;
        r0.w = fmaxf(acc[3] * 0.125f + bi0.w, 0.f) + pr0.w;
        r1.x = fmaxf(acc[4] * 0.125f + bi1.x, 0.f) + pr1.x;
        r1.y = fmaxf(acc[5] * 0.125f + bi1.y, 0.f) + pr1.y;
        r1.z = fmaxf(acc[6] * 0.125f + bi1.z, 0.f) + pr1.z;
        r1.w = fmaxf(acc[7] * 0.125f + bi1.w, 0.f) + pr1.w;
        ((float4*)(xnew + (size_t)d * C_CH))[sl * 2] = r0;
        ((float4*)(xnew + (size_t)d * C_CH))[sl * 2 + 1] = r1;
    }
}

extern "C" void kernel_launch(void* const* d_in, const int* in_sizes, int n_in,
                              void* d_out, int out_size, void* d_ws, size_t ws_size,
                              hipStream_t stream) {
    const float* x         = (const float*)d_in[0];
    const int*   ei        = (const int*)d_in[1];
    const float* edge_attr = (const float*)d_in[2];
    // d_in[3] = batch (unused)
    const float* Wl        = (const float*)d_in[4];
    const float* Wr        = (const float*)d_in[5];
    const float* We        = (const float*)d_in[6];
    const float* att       = (const float*)d_in[7];
    const float* bias      = (const float*)d_in[8];
    const float* Wproj     = (const float*)d_in[9];

    float* ws    = (float*)d_ws;
    unsigned short* xlb  = (unsigned short*)(ws + OFF_XLB);
    unsigned short* xrb  = (unsigned short*)(ws + OFF_XRB);
    float* proj  = ws + OFF_PROJ;
    float* aexp  = ws + OFF_AEXP;
    unsigned short* wcat = (unsigned short*)(ws + OFF_WCAT);
    float* part  = ws + OFF_PART;
    float* meanp = ws + OFF_MEAN;
    int2*  csr2  = (int2*)(ws + OFF_CSR2);
    int*   deg   = (int*)(ws + OFF_DEG);
    int*   offs  = (int*)(ws + OFF_OFFS);
    int*   cur   = (int*)(ws + OFF_CUR);
    int*   bsum  = (int*)(ws + OFF_BSUM);

    float* out_xnew  = (float*)d_out;
    float* out_alpha = (float*)d_out + (size_t)N_NODES * C_CH;

    hipMemsetAsync(deg, 0, N_NODES * sizeof(int), stream);

    pre_kernel<<<1024, 256, 0, stream>>>(Wl, Wr, Wproj, wcat, ei, edge_attr, deg, part);

    {
        void* args[] = {(void*)&ei, (void*)&edge_attr, (void*)&part,
                        (void*)&deg, (void*)&bsum, (void*)&offs, (void*)&cur,
                        (void*)&meanp, (void*)&csr2};
        hipLaunchCooperativeKernel((const void*)csr_build_kernel,
                                   dim3(CSRB), dim3(256), args, 0, stream);
    }

    dim3 ggrid((N_NODES + GM - 1) / GM, (544 + GN - 1) / GN);
    gemm_mfma_kernel<<<ggrid, 256, 0, stream>>>(x, wcat, xlb, xrb, proj);

    node_agg_kernel<<<(N_NODES + 3) / 4, 256, 0, stream>>>(offs, csr2, We, att, xlb, xrb,
                                                           proj, bias, aexp, out_alpha, out_xnew);
}

// Round 16
// 172.979 us; speedup vs baseline: 2.5282x; 2.5282x over previous
//
#include <hip/hip_runtime.h>
#include <math.h>

#define N_NODES 50000
#define N_EDGES 400000
#define EN_TOT  450000
#define IN_DIM  128
#define H_HEADS 8
#define C_CH    32
#define HC      256
#define NEG_SLOPE 0.2f
#define MAXDEG 64      // LDS stash cap; global fallback beyond (max deg here ~30)

typedef __attribute__((ext_vector_type(8))) short bf16x8;
typedef __attribute__((ext_vector_type(4))) float f32x4;

// ---------------- workspace layout (float slots) ----------------
// UNIT DISCIPLINE: sizes in FLOAT slots; bf16 regions = count/2 slots.
#define OFF_XLB   0                                   // x_l bf16 [N,256] -> N*128 floats
#define OFF_XRB   (OFF_XLB + N_NODES * 128)           // x_r bf16 [N,256]
#define OFF_PROJ  (OFF_XRB + N_NODES * 128)           // proj fp32 [N,32]
#define OFF_AEXP  (OFF_PROJ + N_NODES * C_CH)         // aexp [E+N,8] fp32 (overflow fallback only)
#define OFF_WCAT  (OFF_AEXP + EN_TOT * H_HEADS)       // Wcat bf16 [544,128]: 69632 shorts = 34816 floats
#define OFF_PART  (OFF_WCAT + 34816)                  // partial sums [1024]
#define OFF_MEAN  (OFF_PART + 1024)                   // mean scalar [1]
#define OFF_PAD   (OFF_MEAN + 1)                      // pad to 16B boundary
#define OFF_CSR2  (OFF_PAD + 3)                       // packed csr int2 {src|eav_bf16<<16, eid} [E+N]
#define OFF_DEG   (OFF_CSR2 + EN_TOT * 2)             // deg  [N]
#define OFF_OFFS  (OFF_DEG + N_NODES)                 // offs [N+1]
#define OFF_CUR   (OFF_OFFS + N_NODES + 1)            // cursor [N]
#define OFF_BSUM  (OFF_CUR + N_NODES)                 // block sums [256]

#define SCAN_B 196   // ceil(50000/256)
#define LOG2E 1.4426950408889634f

// ---------------- fp32 -> bf16 (RNE) ----------------
__device__ __forceinline__ unsigned f2bf(float f) {
    unsigned u = __float_as_uint(f);
    u += 0x7fffu + ((u >> 16) & 1u);
    return u >> 16;
}
__device__ __forceinline__ float bflo(unsigned u) { return __uint_as_float(u << 16); }
__device__ __forceinline__ float bfhi(unsigned u) { return __uint_as_float(u & 0xffff0000u); }

// ---------------- fused: weight convert + dst-histogram + edge_attr partials ----------------
#define WCHUNKS 8704              // 544*128/8
__global__ __launch_bounds__(256) void pre_kernel(
    const float* __restrict__ Wl, const float* __restrict__ Wr, const float* __restrict__ Wproj,
    unsigned short* __restrict__ wcat,
    const int* __restrict__ ei, const float* __restrict__ ea,
    int* __restrict__ deg, float* __restrict__ part)
{
    __shared__ float sd[256];
    const int t = threadIdx.x;
    const int g = blockIdx.x * 256 + t;

    if (g < WCHUNKS) {
        int j = (g * 8) >> 7, k = (g * 8) & 127;
        const float* src = (j < 256 ? Wl + (size_t)j * 128
                                    : (j < 512 ? Wr + (size_t)(j - 256) * 128
                                               : Wproj + (size_t)(j - 512) * 128)) + k;
        float4 a = ((const float4*)src)[0];
        float4 b = ((const float4*)src)[1];
        uint4 o;
        o.x = f2bf(a.x) | (f2bf(a.y) << 16);
        o.y = f2bf(a.z) | (f2bf(a.w) << 16);
        o.z = f2bf(b.x) | (f2bf(b.y) << 16);
        o.w = f2bf(b.z) | (f2bf(b.w) << 16);
        ((uint4*)wcat)[g] = o;
    }

    float s = 0.f;
    for (int i = g; i < N_EDGES; i += 1024 * 256) s += ea[i];
    for (int i = g; i < EN_TOT; i += 1024 * 256) {
        int d = (i < N_EDGES) ? ei[N_EDGES + i] : (i - N_EDGES);
        atomicAdd(&deg[d], 1);
    }
    sd[t] = s; __syncthreads();
    for (int w = 128; w > 0; w >>= 1) { if (t < w) sd[t] += sd[t + w]; __syncthreads(); }
    if (t == 0) part[blockIdx.x] = sd[0];
}

// ---------------- parallel 3-phase exclusive scan of deg[50000] ----------------
__global__ __launch_bounds__(256) void scan_part_kernel(const int* __restrict__ deg,
                                                        int* __restrict__ bsum) {
    __shared__ int sd[256];
    int t = threadIdx.x;
    int i = blockIdx.x * 256 + t;
    int v = (i < N_NODES) ? deg[i] : 0;
    sd[t] = v; __syncthreads();
    for (int w = 128; w > 0; w >>= 1) { if (t < w) sd[t] += sd[t + w]; __syncthreads(); }
    if (t == 0) bsum[blockIdx.x] = sd[0];
}

// fused: scan of block sums + edge_attr mean finalize (both single-block)
__global__ __launch_bounds__(256) void mid_kernel(int* __restrict__ bsum,
                                                  const float* __restrict__ part,
                                                  float* __restrict__ mean_out) {
    __shared__ int sd[256];
    __shared__ float sf[256];
    int t = threadIdx.x;
    float s = part[t] + part[t + 256] + part[t + 512] + part[t + 768];
    sf[t] = s;
    int v = (t < SCAN_B) ? bsum[t] : 0;
    sd[t] = v; __syncthreads();
    for (int w = 128; w > 0; w >>= 1) { if (t < w) sf[t] += sf[t + w]; __syncthreads(); }
    if (t == 0) mean_out[0] = sf[0] / (float)N_EDGES;
    #pragma unroll
    for (int ofs = 1; ofs < 256; ofs <<= 1) {
        int u = (t >= ofs) ? sd[t - ofs] : 0;
        __syncthreads();
        sd[t] += u;
        __syncthreads();
    }
    if (t < SCAN_B) bsum[t] = sd[t] - v;   // exclusive
}

__global__ __launch_bounds__(256) void scan_final_kernel(
    const int* __restrict__ deg, const int* __restrict__ bsum,
    int* __restrict__ offs, int* __restrict__ cur) {
    __shared__ int sd[256];
    int t = threadIdx.x;
    int i = blockIdx.x * 256 + t;
    int v = (i < N_NODES) ? deg[i] : 0;
    sd[t] = v; __syncthreads();
    #pragma unroll
    for (int ofs = 1; ofs < 256; ofs <<= 1) {
        int u = (t >= ofs) ? sd[t - ofs] : 0;
        __syncthreads();
        sd[t] += u;
        __syncthreads();
    }
    int excl = bsum[blockIdx.x] + sd[t] - v;
    if (i < N_NODES) { offs[i] = excl; cur[i] = excl; }
    if (i == N_NODES - 1) offs[N_NODES] = excl + v;
}

// ---------------- scatter into packed CSR: int2 {src | eav_bf16<<16, eid} ----------------
__global__ __launch_bounds__(256) void scatter_kernel(
    const int* __restrict__ ei, const float* __restrict__ edge_attr,
    const float* __restrict__ mean_attr, int* __restrict__ cur,
    int2* __restrict__ csr2)
{
    int e = blockIdx.x * 256 + threadIdx.x;
    if (e >= EN_TOT) return;
    int s, d; float eav;
    if (e < N_EDGES) { s = ei[e]; d = ei[N_EDGES + e]; eav = edge_attr[e]; }
    else { s = e - N_EDGES; d = s; eav = mean_attr[0]; }
    int pos = atomicAdd(&cur[d], 1);
    csr2[pos] = make_int2(s | (int)(f2bf(eav) << 16), e);   // src < 65536 OK (N=50000)
}

// ---------------- MFMA GEMM: fp32 x converted inline, bf16 out xl/xr, fp32 proj ----------------
// Epilogue: bf16 tiles staged in LDS (stride 72 shorts, 16B-aligned), then 16B
// coalesced uint4 stores (8x fewer store instructions than per-element shorts).
#define GM 128
#define GN 64
#define CST 72   // C-staging stride in shorts (144B rows)

__global__ __launch_bounds__(256) void gemm_mfma_kernel(
    const float* __restrict__ x, const unsigned short* __restrict__ wcat,
    unsigned short* __restrict__ xlb, unsigned short* __restrict__ xrb,
    float* __restrict__ proj)
{
    __shared__ unsigned short As[GM * 128];   // 32 KB (staging A; reused for C)
    __shared__ unsigned short Bs[GN * 128];   // 16 KB
    const int t = threadIdx.x;
    const int m0 = blockIdx.x * GM;
    const int n0 = blockIdx.y * GN;

    #pragma unroll
    for (int cc = 0; cc < 8; ++cc) {
        int c = t + cc * 256;
        int r = c >> 4;
        int k0 = (c & 15) * 8;
        int row = m0 + r;
        uint4 o = make_uint4(0, 0, 0, 0);
        if (row < N_NODES) {
            const float* p = x + (size_t)row * IN_DIM + k0;
            float4 a = ((const float4*)p)[0];
            float4 b = ((const float4*)p)[1];
            o.x = f2bf(a.x) | (f2bf(a.y) << 16);
            o.y = f2bf(a.z) | (f2bf(a.w) << 16);
            o.z = f2bf(b.x) | (f2bf(b.y) << 16);
            o.w = f2bf(b.z) | (f2bf(b.w) << 16);
        }
        int byte = (r * 256 + k0 * 2) ^ ((r & 7) << 4);
        *((uint4*)((char*)As + byte)) = o;
    }
    #pragma unroll
    for (int cc = 0; cc < 4; ++cc) {
        int c = t + cc * 256;
        int r = c >> 4;
        int k0 = (c & 15) * 8;
        int j = n0 + r;
        uint4 v = make_uint4(0, 0, 0, 0);
        if (j < 544) v = *((const uint4*)(wcat + (size_t)j * 128 + k0));
        int byte = (r * 256 + k0 * 2) ^ ((r & 7) << 4);
        *((uint4*)((char*)Bs + byte)) = v;
    }
    __syncthreads();

    const int wid = t >> 6, lane = t & 63;
    const int wr = wid >> 1, wc = wid & 1;
    const int lrow = lane & 15;
    const int kgrp = (lane >> 4) * 8;

    f32x4 acc[4][2] = {};
    #pragma unroll
    for (int kk = 0; kk < 4; ++kk) {
        bf16x8 a[4], b[2];
        #pragma unroll
        for (int fm = 0; fm < 4; ++fm) {
            int r = wr * 64 + fm * 16 + lrow;
            int byte = (r * 256 + (kk * 32 + kgrp) * 2) ^ ((r & 7) << 4);
            a[fm] = *((const bf16x8*)((const char*)As + byte));
        }
        #pragma unroll
        for (int fn = 0; fn < 2; ++fn) {
            int r = wc * 32 + fn * 16 + lrow;
            int byte = (r * 256 + (kk * 32 + kgrp) * 2) ^ ((r & 7) << 4);
            b[fn] = *((const bf16x8*)((const char*)Bs + byte));
        }
        #pragma unroll
        for (int fm = 0; fm < 4; ++fm)
            #pragma unroll
            for (int fn = 0; fn < 2; ++fn)
                acc[fm][fn] = __builtin_amdgcn_mfma_f32_16x16x32_bf16(a[fm], b[fn], acc[fm][fn], 0, 0, 0);
    }

    // C layout: row = (lane>>4)*4 + reg, col = lane&15  (m89-verified)
    const int crow0 = (lane >> 4) * 4;
    const int ccol = lane & 15;

    if (n0 < 512) {
        __syncthreads();   // all MFMA reads of As complete
        unsigned short* Cs = As;   // [GM][CST] shorts
        #pragma unroll
        for (int fm = 0; fm < 4; ++fm)
            #pragma unroll
            for (int fn = 0; fn < 2; ++fn)
                #pragma unroll
                for (int r = 0; r < 4; ++r) {
                    int lr = wr * 64 + fm * 16 + crow0 + r;    // 0..127
                    int lc = wc * 32 + fn * 16 + ccol;         // 0..63
                    Cs[lr * CST + lc] = (unsigned short)f2bf(acc[fm][fn][r]);
                }
        __syncthreads();
        unsigned short* dst = (n0 < 256) ? xlb : xrb;
        const int colbase = n0 & 255;
        #pragma unroll
        for (int cc = 0; cc < 4; ++cc) {
            int c = t + cc * 256;        // 0..1023
            int r = c >> 3;              // 0..127
            int c8 = (c & 7) * 8;        // col 0,8,..,56
            int row = m0 + r;
            if (row < N_NODES) {
                uint4 v = *((const uint4*)(Cs + r * CST + c8));
                *((uint4*)(dst + (size_t)row * HC + colbase + c8)) = v;
            }
        }
    } else {
        #pragma unroll
        for (int fm = 0; fm < 4; ++fm)
            #pragma unroll
            for (int fn = 0; fn < 2; ++fn)
                #pragma unroll
                for (int r = 0; r < 4; ++r) {
                    int row = m0 + wr * 64 + fm * 16 + crow0 + r;
                    int col = n0 + wc * 32 + fn * 16 + ccol;
                    if (row >= N_NODES || col >= 544) continue;
                    proj[(size_t)row * C_CH + (col - 512)] = acc[fm][fn][r];
                }
    }
}

// ---------------- fused node aggregation: scalar math + int2 CSR + exp2 fold + LDS stash ----------------
// One wave per node; 32 lanes/edge (8 ch/lane), 2 edges/wave-step, 1-pair pipeline.
// Scalar math (packed-f32 regressed twice: r9, r12). att pre-scaled by LOG2E so
// exp2f = bare v_exp_f32. aexp/eid stashed in per-wave LDS. STRUCTURAL FLOOR:
// VALUBusy ~83%, 5 variants (r8-r12) all >= 69.4us. Cooperative fusion of the
// CSR-build regressed 173->437us (grid.sync ~90us/barrier on 8 XCDs) — kernel
// boundaries ARE the cheap grid barrier on gfx950.
__global__ __launch_bounds__(256) void node_agg_kernel(
    const int* __restrict__ offs, const int2* __restrict__ csr2,
    const float* __restrict__ We, const float* __restrict__ att,
    const unsigned short* __restrict__ xlb, const unsigned short* __restrict__ xrb,
    const float* __restrict__ proj, const float* __restrict__ bias,
    float* __restrict__ aexp_ovf, float* __restrict__ alpha_out, float* __restrict__ xnew)
{
    __shared__ float s_aexp[4][MAXDEG][H_HEADS];   // 8 KB
    __shared__ int   s_eid[4][MAXDEG];             // 1 KB
    const int w = threadIdx.x >> 6;
    const int l = threadIdx.x & 63;
    const int d = blockIdx.x * 4 + w;
    if (d >= N_NODES) return;
    const int half = l >> 5;     // which edge of the pair this lane works on
    const int sl = l & 31;       // channel block: ch sl*8 .. sl*8+7 (head sl>>2)

    const float4 we0 = ((const float4*)We)[sl * 2];
    const float4 we1 = ((const float4*)We)[sl * 2 + 1];
    const float4 at0 = ((const float4*)att)[sl * 2];
    const float4 at1 = ((const float4*)att)[sl * 2 + 1];
    const float wev[8] = {we0.x, we0.y, we0.z, we0.w, we1.x, we1.y, we1.z, we1.w};
    const float atv[8] = {at0.x * LOG2E, at0.y * LOG2E, at0.z * LOG2E, at0.w * LOG2E,
                          at1.x * LOG2E, at1.y * LOG2E, at1.z * LOG2E, at1.w * LOG2E};

    const uint4 vru = ((const uint4*)(xrb + (size_t)d * HC))[sl];
    float vr[8];
    vr[0] = bflo(vru.x); vr[1] = bfhi(vru.x); vr[2] = bflo(vru.y); vr[3] = bfhi(vru.y);
    vr[4] = bflo(vru.z); vr[5] = bfhi(vru.z); vr[6] = bflo(vru.w); vr[7] = bfhi(vru.w);

    const int beg = offs[d];
    const int end = offs[d + 1];

    float acc[8] = {0.f, 0.f, 0.f, 0.f, 0.f, 0.f, 0.f, 0.f};
    float den = 0.f;

    int i = beg;
    int2 c0 = make_int2(0, 0);
    uint4 vl0 = make_uint4(0, 0, 0, 0);
    if (i + half < end) {
        c0 = csr2[i + half];
        vl0 = ((const uint4*)(xlb + (size_t)(c0.x & 0xffff) * HC))[sl];
    }
    while (i < end) {
        const int ni = i + 2;
        int2 c1 = make_int2(0, 0);
        uint4 vl1 = make_uint4(0, 0, 0, 0);
        if (ni + half < end) {
            c1 = csr2[ni + half];
            vl1 = ((const uint4*)(xlb + (size_t)(c1.x & 0xffff) * HC))[sl];
        }

        const float ea = bfhi((unsigned)c0.x);   // eav bf16 in high 16 bits
        float xv[8];
        xv[0] = bflo(vl0.x); xv[1] = bfhi(vl0.x); xv[2] = bflo(vl0.y); xv[3] = bfhi(vl0.y);
        xv[4] = bflo(vl0.z); xv[5] = bfhi(vl0.z); xv[6] = bflo(vl0.w); xv[7] = bfhi(vl0.w);

        float tt = 0.f;
        #pragma unroll
        for (int j = 0; j < 8; ++j) {
            float m = xv[j] + vr[j] + ea * wev[j];
            m = fmaxf(m, NEG_SLOPE * m);      // leaky_relu (slope<1)
            tt += m * atv[j];
        }
        tt += __shfl_xor(tt, 1);
        tt += __shfl_xor(tt, 2);
        float aex = exp2f(tt);                // v_exp_f32; LOG2E folded into atv
        const bool valid = (i + half) < end;
        aex = valid ? aex : 0.f;
        const int li = i + half - beg;        // local edge index within node
        if (valid && (sl & 3) == 0) {
            if (li < MAXDEG) s_aexp[w][li][sl >> 2] = aex;
            else             aexp_ovf[(size_t)c0.y * H_HEADS + (sl >> 2)] = aex;
        }
        if (valid && sl == 0 && li < MAXDEG) s_eid[w][li] = c0.y;
        #pragma unroll
        for (int j = 0; j < 8; ++j) acc[j] += aex * xv[j];
        den += aex;

        c0 = c1; vl0 = vl1; i = ni;
    }

    // merge the two edge-halves (same channels, same head)
    den += __shfl_xor(den, 32);
    #pragma unroll
    for (int j = 0; j < 8; ++j) acc[j] += __shfl_xor(acc[j], 32);

    // ---- fused alpha from LDS stash: lane 4h holds den of head h
    const float den_h = __shfl(den, ((l & 7) << 2));
    const float rden = 1.f / den_h;
    for (int b = beg; b < end; b += 8) {
        const int idx = b + (l >> 3);
        if (idx < end) {
            const int li = idx - beg;
            int e; float ax;
            if (li < MAXDEG) { e = s_eid[w][li]; ax = s_aexp[w][li][l & 7]; }
            else { e = csr2[idx].y; ax = aexp_ovf[(size_t)e * H_HEADS + (l & 7)]; }
            alpha_out[(size_t)e * H_HEADS + (l & 7)] = ax * rden;
        }
    }

    // ---- normalize per head, mean over heads, epilogue
    const float inv = 1.f / den;
    #pragma unroll
    for (int j = 0; j < 8; ++j) acc[j] *= inv;
    #pragma unroll
    for (int mask = 4; mask <= 16; mask <<= 1)
        #pragma unroll
        for (int j = 0; j < 8; ++j) acc[j] += __shfl_xor(acc[j], mask);
    // lane sl (<4, half 0) holds head-summed channels sl*8 .. sl*8+7
    if (half == 0 && sl < 4) {
        const float4 bi0 = ((const float4*)bias)[sl * 2];
        const float4 bi1 = ((const float4*)bias)[sl * 2 + 1];
        const float4 pr0 = ((const float4*)(proj + (size_t)d * C_CH))[sl * 2];
        const float4 pr1 = ((const float4*)(proj + (size_t)d * C_CH))[sl * 2 + 1];
        float4 r0, r1;
        r0.x = fmaxf(acc[0] * 0.125f + bi0.x, 0.f) + pr0.x;
        r0.y = fmaxf(acc[1] * 0.125f + bi0.y, 0.f) + pr0.y;
        r0.z = fmaxf(acc[2] * 0.125f + bi0.z, 0.f) + pr0.z;
        r0.w = fmaxf(acc[3] * 0.125f + bi0.w, 0.f) + pr0.w;
        r1.x = fmaxf(acc[4] * 0.125f + bi1.x, 0.f) + pr1.x;
        r1.y = fmaxf(acc[5] * 0.125f + bi1.y, 0.f) + pr1.y;
        r1.z = fmaxf(acc[6] * 0.125f + bi1.z, 0.f) + pr1.z;
        r1.w = fmaxf(acc[7] * 0.125f + bi1.w, 0.f) + pr1.w;
        ((float4*)(xnew + (size_t)d * C_CH))[sl * 2] = r0;
        ((float4*)(xnew + (size_t)d * C_CH))[sl * 2 + 1] = r1;
    }
}

extern "C" void kernel_launch(void* const* d_in, const int* in_sizes, int n_in,
                              void* d_out, int out_size, void* d_ws, size_t ws_size,
                              hipStream_t stream) {
    const float* x         = (const float*)d_in[0];
    const int*   ei        = (const int*)d_in[1];
    const float* edge_attr = (const float*)d_in[2];
    // d_in[3] = batch (unused)
    const float* Wl        = (const float*)d_in[4];
    const float* Wr        = (const float*)d_in[5];
    const float* We        = (const float*)d_in[6];
    const float* att       = (const float*)d_in[7];
    const float* bias      = (const float*)d_in[8];
    const float* Wproj     = (const float*)d_in[9];

    float* ws    = (float*)d_ws;
    unsigned short* xlb  = (unsigned short*)(ws + OFF_XLB);
    unsigned short* xrb  = (unsigned short*)(ws + OFF_XRB);
    float* proj  = ws + OFF_PROJ;
    float* aexp  = ws + OFF_AEXP;
    unsigned short* wcat = (unsigned short*)(ws + OFF_WCAT);
    float* part  = ws + OFF_PART;
    float* meanp = ws + OFF_MEAN;
    int2*  csr2  = (int2*)(ws + OFF_CSR2);
    int*   deg   = (int*)(ws + OFF_DEG);
    int*   offs  = (int*)(ws + OFF_OFFS);
    int*   cur   = (int*)(ws + OFF_CUR);
    int*   bsum  = (int*)(ws + OFF_BSUM);

    float* out_xnew  = (float*)d_out;
    float* out_alpha = (float*)d_out + (size_t)N_NODES * C_CH;

    hipMemsetAsync(deg, 0, N_NODES * sizeof(int), stream);

    pre_kernel<<<1024, 256, 0, stream>>>(Wl, Wr, Wproj, wcat, ei, edge_attr, deg, part);

    scan_part_kernel<<<SCAN_B, 256, 0, stream>>>(deg, bsum);
    mid_kernel<<<1, 256, 0, stream>>>(bsum, part, meanp);
    scan_final_kernel<<<SCAN_B, 256, 0, stream>>>(deg, bsum, offs, cur);

    scatter_kernel<<<(EN_TOT + 255) / 256, 256, 0, stream>>>(ei, edge_attr, meanp, cur, csr2);

    dim3 ggrid((N_NODES + GM - 1) / GM, (544 + GN - 1) / GN);
    gemm_mfma_kernel<<<ggrid, 256, 0, stream>>>(x, wcat, xlb, xrb, proj);

    node_agg_kernel<<<(N_NODES + 3) / 4, 256, 0, stream>>>(offs, csr2, We, att, xlb, xrb,
                                                           proj, bias, aexp, out_alpha, out_xnew);
}